// Round 8
// baseline (2454.459 us; speedup 1.0000x reference)
//
#include <hip/hip_runtime.h>

// LSTM B=512, T=512, H=256. Round 8 = r7 + IN-LOOP asm re-pin of weight regs.
// r7 lesson: a pin-once asm doesn't prevent the allocator from spilling the
// weight tier after the asm site (VGPR_Count=128, weights remat from L2/step,
// = r4's 384 KB/step VMEM straw). Fix: re-assert "+v" liveness on all 128
// weight dwords INSIDE the t-loop -> spilling costs 128 reloads/step, so the
// allocator keeps them resident (128 pinned + ~110 working < 256 budget).
// 32 blocks x 512 thr (8 waves, 2/SIMD). Wave owns 32 gate-cols (nt=g*2+e).
// Tiers/wave: kt 0..3 pinned regs | kt 4..5 LDS (128 KB) | kt 6..7 L2 stream.
// MFMA f32_16x16x32_f16: A=h[m=batch=l16][k], B=W[k][n=col=l16], D[m=quad*4+r][n].
// Weights prescaled by -log2e (i,f,o) / +2log2e (g) => nonlinearity is exp2-only.

typedef _Float16 half8 __attribute__((ext_vector_type(8)));
typedef float f32x4 __attribute__((ext_vector_type(4)));
typedef float f32x2 __attribute__((ext_vector_type(2)));

constexpr int kT = 512;
constexpr int kHP = 272;   // h_lds row stride (halves), 544 B
constexpr float kLog2e = 1.44269504088896340736f;

// ws layout, half8 units (16 B):
//   REG  [0,16384):     f = w*32 + nt*4 + kt          (kt 0..3)
//   LDSW [16384,24576): f = w*16 + nt*2 + (kt-4)      (kt 4..5)
//   STRM [24576,32768): f = w*16 + nt*2 + (kt-6)      (kt 6..7)
// element: nt=g*2+e, col R = g*256 + w*32 + 2*(lane&15) + e, k = kt*32 + (lane>>4)*8 + j
__global__ void prep_weights(const float* __restrict__ W_hh, _Float16* __restrict__ ws)
{
    int gid = blockIdx.x * blockDim.x + threadIdx.x;  // 0..32767
    int lane = gid & 63;
    int w, nt, kt;
    if (gid < 16384) {
        int f = gid >> 6;
        kt = f & 3; nt = (f >> 2) & 7; w = f >> 5;
    } else if (gid < 24576) {
        int f = (gid - 16384) >> 6;
        kt = 4 + (f & 1); nt = (f >> 1) & 7; w = f >> 4;
    } else {
        int f = (gid - 24576) >> 6;
        kt = 6 + (f & 1); nt = (f >> 1) & 7; w = f >> 4;
    }
    int g = nt >> 1, e = nt & 1;
    int r = g * 256 + w * 32 + 2 * (lane & 15) + e;
    int k = kt * 32 + (lane >> 4) * 8;
    float s = (g == 2) ? 2.0f * kLog2e : -kLog2e;
    const float* src = W_hh + r * 256 + k;
    half8 v;
    #pragma unroll
    for (int j = 0; j < 8; ++j) v[j] = (_Float16)(src[j] * s);
    reinterpret_cast<half8*>(ws)[gid] = v;
}

__device__ __forceinline__ f32x4 mfma16(half8 a, half8 b, f32x4 c) {
    return __builtin_amdgcn_mfma_f32_16x16x32_f16(a, b, c, 0, 0, 0);
}
__device__ __forceinline__ f32x2 unpack2(unsigned int u) {
    union { unsigned int u; _Float16 h[2]; } cv; cv.u = u;
    f32x2 r; r.x = (float)cv.h[0]; r.y = (float)cv.h[1]; return r;
}

__global__ __launch_bounds__(512, 2)
void lstm_main(const float* __restrict__ ts,
               const float* __restrict__ W_ih,
               const float* __restrict__ b_ih,
               const float* __restrict__ b_hh,
               const float* __restrict__ W_out,
               const float* __restrict__ b_out,
               const _Float16* __restrict__ wfrag,
               float* __restrict__ out)
{
    __shared__ __align__(16) _Float16 wlds[65536];        // 128 KB (kt 4..5)
    __shared__ __align__(16) _Float16 h_lds[2][16][kHP];  // 17 KB
    __shared__ float red[8][16];

    const int tid  = threadIdx.x;
    const int w    = tid >> 6;       // wave 0..7
    const int lane = tid & 63;
    const int l16  = lane & 15;
    const int quad = lane >> 4;
    const int b0   = blockIdx.x * 16;

    const half8* wf8 = reinterpret_cast<const half8*>(wfrag);
    half8* wlds8 = reinterpret_cast<half8*>(wlds);

    // stage LDS weight tier (one-time)
    for (int i = tid; i < 8192; i += 512) wlds8[i] = wf8[16384 + i];
    // zero h parity-1 buffer (t=0 reads parity 1)
    for (int i = tid; i < 16 * kHP; i += 512)
        (&h_lds[1][0][0])[i] = (_Float16)0.0f;

    // ---- PINNED register tier: 32 frags x 4 dwords = 128 VGPRs/lane ----
    unsigned int wr_[32][4];
    {
        const uint4* wsrc = reinterpret_cast<const uint4*>(wfrag);
        #pragma unroll
        for (int i = 0; i < 32; ++i) {
            uint4 v = wsrc[(w * 32 + i) * 64 + lane];
            wr_[i][0] = v.x; wr_[i][1] = v.y; wr_[i][2] = v.z; wr_[i][3] = v.w;
            asm volatile("" : "+v"(wr_[i][0]), "+v"(wr_[i][1]), "+v"(wr_[i][2]), "+v"(wr_[i][3]));
        }
    }

    // per-col scalars packed fp16 {wih*s, bias*s} (col = w*32 + 2*l16 + e, nt=g*2+e)
    unsigned int wb16[8];
    #pragma unroll
    for (int nt = 0; nt < 8; ++nt) {
        int g = nt >> 1, e = nt & 1;
        int R = g * 256 + w * 32 + 2 * l16 + e;
        float s = (g == 2) ? 2.0f * kLog2e : -kLog2e;
        union { unsigned int u; _Float16 h[2]; } cv;
        cv.h[0] = (_Float16)(W_ih[R] * s);
        cv.h[1] = (_Float16)((b_ih[R] + b_hh[R]) * s);
        wb16[nt] = cv.u;
    }

    const half8* sps = wf8 + 24576 + w * 1024 + lane;   // STRM: frag (nt,j) at sps[(nt*2+j)*64]

    float cst[8] = {0,0,0,0,0,0,0,0};
    float oacc[4] = {0.f, 0.f, 0.f, 0.f};

    __syncthreads();

    for (int t = 0; t < kT; ++t) {
        const int rp = (t + 1) & 1, wp = t & 1;

        // IN-LOOP RE-PIN: all 128 weight dwords must be register-live here,
        // every iteration -> spilling them is 128 reloads/step, allocator
        // keeps them resident instead.
        #pragma unroll
        for (int i = 0; i < 32; ++i)
            asm volatile("" : "+v"(wr_[i][0]), "+v"(wr_[i][1]), "+v"(wr_[i][2]), "+v"(wr_[i][3]));

        // A fragments (h) from LDS
        half8 a[8];
        #pragma unroll
        for (int kt = 0; kt < 8; ++kt)
            a[kt] = *reinterpret_cast<const half8*>(&h_lds[rp][l16][kt * 32 + quad * 8]);

        float tsv[4];
        #pragma unroll
        for (int r = 0; r < 4; ++r) tsv[r] = ts[(b0 + quad * 4 + r) * kT + t];
        f32x2 wo = *reinterpret_cast<const f32x2*>(&W_out[t * 256 + w * 32 + 2 * l16]);

        float hv0[4];
        #pragma unroll
        for (int e = 0; e < 2; ++e) {
            // stream tier loads for this e: nt = g*2+e, kt 6..7 (issued first, consumed last)
            half8 s6[4], s7[4];
            #pragma unroll
            for (int g = 0; g < 4; ++g) {
                int nt = g * 2 + e;
                s6[g] = sps[(nt * 2 + 0) * 64];
                s7[g] = sps[(nt * 2 + 1) * 64];
            }
            f32x4 gacc[4];
            #pragma unroll
            for (int g = 0; g < 4; ++g) { f32x4 z = {0.f,0.f,0.f,0.f}; gacc[g] = z; }
            // reg tier (kt-outer => 4 independent chains)
            #pragma unroll
            for (int kt = 0; kt < 4; ++kt)
                #pragma unroll
                for (int g = 0; g < 4; ++g) {
                    int fi = (g * 2 + e) * 4 + kt;
                    half8 wv = __builtin_bit_cast(half8,
                        make_uint4(wr_[fi][0], wr_[fi][1], wr_[fi][2], wr_[fi][3]));
                    gacc[g] = mfma16(a[kt], wv, gacc[g]);
                }
            // LDS tier
            #pragma unroll
            for (int kk = 0; kk < 2; ++kk)
                #pragma unroll
                for (int g = 0; g < 4; ++g) {
                    int nt = g * 2 + e;
                    half8 lw = wlds8[(w * 16 + nt * 2 + kk) * 64 + lane];
                    gacc[g] = mfma16(a[4 + kk], lw, gacc[g]);
                }
            // stream tier
            #pragma unroll
            for (int g = 0; g < 4; ++g) gacc[g] = mfma16(a[6], s6[g], gacc[g]);
            #pragma unroll
            for (int g = 0; g < 4; ++g) gacc[g] = mfma16(a[7], s7[g], gacc[g]);

            // nonlinearity: lane owns (batch = quad*4+r, col = w*32 + 2*l16 + e)
            f32x2 ib[4];
            #pragma unroll
            for (int g = 0; g < 4; ++g) ib[g] = unpack2(wb16[g * 2 + e]);
            #pragma unroll
            for (int r = 0; r < 4; ++r) {
                float gi = gacc[0][r] + (tsv[r] * ib[0].x + ib[0].y);
                float gf = gacc[1][r] + (tsv[r] * ib[1].x + ib[1].y);
                float gg = gacc[2][r] + (tsv[r] * ib[2].x + ib[2].y);
                float go = gacc[3][r] + (tsv[r] * ib[3].x + ib[3].y);
                float I = __builtin_amdgcn_rcpf(1.0f + __builtin_amdgcn_exp2f(gi));
                float F = __builtin_amdgcn_rcpf(1.0f + __builtin_amdgcn_exp2f(gf));
                float G = 1.0f - 2.0f * __builtin_amdgcn_rcpf(1.0f + __builtin_amdgcn_exp2f(gg));
                float O = __builtin_amdgcn_rcpf(1.0f + __builtin_amdgcn_exp2f(go));
                float c = F * cst[e * 4 + r] + I * G;
                cst[e * 4 + r] = c;
                float tc = 1.0f - 2.0f * __builtin_amdgcn_rcpf(
                               1.0f + __builtin_amdgcn_exp2f(2.0f * kLog2e * c));
                float hv = O * tc;
                oacc[r] += hv * (e ? wo.y : wo.x);
                if (e == 0) hv0[r] = hv;
                else {
                    union { unsigned int u; _Float16 h[2]; } hp;
                    hp.h[0] = (_Float16)hv0[r];
                    hp.h[1] = (_Float16)hv;
                    *reinterpret_cast<unsigned int*>(
                        &h_lds[wp][quad * 4 + r][w * 32 + 2 * l16]) = hp.u;
                }
            }
        }
        __syncthreads();
    }

    // reduce oacc over l16 lanes (cols), then waves
    #pragma unroll
    for (int r = 0; r < 4; ++r) {
        float v = oacc[r];
        v += __shfl_xor(v, 1, 64);
        v += __shfl_xor(v, 2, 64);
        v += __shfl_xor(v, 4, 64);
        v += __shfl_xor(v, 8, 64);
        oacc[r] = v;
    }
    if (l16 == 0) {
        #pragma unroll
        for (int r = 0; r < 4; ++r) red[w][quad * 4 + r] = oacc[r];
    }
    __syncthreads();
    if (tid < 16) {
        float s = b_out[0];
        #pragma unroll
        for (int ww = 0; ww < 8; ++ww) s += red[ww][tid];
        out[b0 + tid] = s;
    }
}

extern "C" void kernel_launch(void* const* d_in, const int* in_sizes, int n_in,
                              void* d_out, int out_size, void* d_ws, size_t ws_size,
                              hipStream_t stream) {
    const float* ts    = (const float*)d_in[0];
    const float* W_ih  = (const float*)d_in[1];
    const float* W_hh  = (const float*)d_in[2];
    const float* b_ih  = (const float*)d_in[3];
    const float* b_hh  = (const float*)d_in[4];
    const float* W_out = (const float*)d_in[5];
    const float* b_out = (const float*)d_in[6];
    _Float16* wfrag = (_Float16*)d_ws;   // 512 KB of fragments

    prep_weights<<<128, 256, 0, stream>>>(W_hh, wfrag);
    lstm_main<<<32, 512, 0, stream>>>(ts, W_ih, b_ih, b_hh, W_out, b_out,
                                      wfrag, (float*)d_out);
}